// Round 2
// baseline (425.287 us; speedup 1.0000x reference)
//
#include <hip/hip_runtime.h>
#include <hip/hip_bf16.h>

// Dual-stage topic attention. f32 I/O, bf16 intermediates.
//   Xb = bf16(x); Wb* = bf16(W*)   (one merged cvt dispatch)
//   Mx = segmean(x); Mb = Mx + Mx@Wc^T + bc; Mq = Mb@Wq^T
//   [Q|K|V] = Xb @ [Wq|Wk|Wv]^T + bias
//   T = Q + Mq[seg] (on the fly)
//   VT = attn(T,K,V) -> d_out[0:half) ; CTX = attn(Q,T,VT) -> K slot
//   out = CTX @ Wo^T + bo (f32)
// r14 (single structural change vs r13): QKV + Wo GEMMs moved to a new
// 256x256-tile core (gemm_core256): 512 threads / 8 waves, BK=32, 4-slot
// LDS ring (128KB), 3 K-tiles prefetched ahead, COUNTED s_waitcnt vmcnt(8)
// + raw s_barrier per K-iter (T3+T4 — loads stay in flight across
// barriers; __syncthreads' vmcnt(0) drain was the 27.5% MfmaUtil ceiling),
// setprio around the 32-MFMA cluster (T5), and a fragment-contiguous LDS
// layout staged via per-lane-permuted global source addresses so every
// ds_read_b128 is lane-linear => zero bank conflicts (T2; r13 measured
// 7.08M conflict cycles). Fragment<->lane math identical to r13 (verified).
// Small Mx GEMMs stay on the old verified 128^2 core.

typedef __bf16 bf16_t;
typedef __bf16 bf16x8 __attribute__((ext_vector_type(8)));
typedef __bf16 bf16x4 __attribute__((ext_vector_type(4)));
typedef float f32x4 __attribute__((ext_vector_type(4)));

#define B_ 32
#define N_ 512
#define D_ 768
#define H_ 12
#define HD_ 64
#define K_ 8
#define ND_ (N_ * D_)   // 393216

typedef __attribute__((address_space(1))) unsigned int as1_u32;
typedef __attribute__((address_space(3))) unsigned int as3_u32;

__device__ __forceinline__ void glds16(const void* g, void* l) {
  // async global->LDS, 16B/lane; LDS dest = wave-uniform base + lane*16
  __builtin_amdgcn_global_load_lds((as1_u32*)g, (as3_u32*)l, 16, 0, 0);
}

__device__ __forceinline__ f32x4 mfma16(bf16x8 a, bf16x8 b, f32x4 c) {
  return __builtin_amdgcn_mfma_f32_16x16x32_bf16(a, b, c, 0, 0, 0);
}

__device__ __forceinline__ bf16x8 addv8(bf16x8 a, bf16x8 b) {
  bf16x8 o;
#pragma unroll
  for (int j = 0; j < 8; ++j) o[j] = (bf16_t)((float)a[j] + (float)b[j]);
  return o;
}

// tid int32 or int64; int64 => word[1] (high half of elem0) == 0 (values 1..8).
__device__ __forceinline__ int seg_of(const int* tid, int b) {
  const bool is64 = (tid[1] == 0);
  int v = is64 ? (int)((const long long*)tid)[b] : tid[b];
  return v - 1;
}

// One dispatch: convert X (6144 blocks) + 5 weight matrices (288 each).
__global__ __launch_bounds__(256) void k_cvt_all(
    const float* __restrict__ x, const float* __restrict__ Wq,
    const float* __restrict__ Wk, const float* __restrict__ Wv,
    const float* __restrict__ Wc, const float* __restrict__ Wo,
    bf16_t* __restrict__ Xb, bf16_t* __restrict__ Wqb,
    bf16_t* __restrict__ Wkb, bf16_t* __restrict__ Wvb,
    bf16_t* __restrict__ Wcb, bf16_t* __restrict__ Wob) {
  int bid = blockIdx.x;
  const float* in;
  bf16_t* out;
  if (bid < 6144) {
    in = x; out = Xb;
  } else {
    const int wi = (bid - 6144) / 288;
    bid = (bid - 6144) % 288;
    in = wi == 0 ? Wq : wi == 1 ? Wk : wi == 2 ? Wv : wi == 3 ? Wc : Wo;
    out = wi == 0 ? Wqb : wi == 1 ? Wkb : wi == 2 ? Wvb : wi == 3 ? Wcb : Wob;
  }
  const size_t i = ((size_t)bid * 256 + threadIdx.x) * 8;
  f32x4 a = *(const f32x4*)(in + i);
  f32x4 b = *(const f32x4*)(in + i + 4);
  bf16x8 o;
#pragma unroll
  for (int j = 0; j < 4; ++j) { o[j] = (bf16_t)a[j]; o[4 + j] = (bf16_t)b[j]; }
  *(bf16x8*)(out + i) = o;
}

// ---------------------------------------------------------------------------
// OLD GEMM core (128x128, verified): used only for the two tiny Mx GEMMs.
// ---------------------------------------------------------------------------
__device__ __forceinline__ void gemm_core(const bf16_t* __restrict__ A,
                                          const bf16_t* __restrict__ Bw,
                                          char* smem, f32x4 (&acc)[4][4]) {
  const int t = threadIdx.x;
  const int lane = t & 63, w = t >> 6;
  const int quad = lane >> 4, l15 = lane & 15;
  const int r0 = t >> 2;
  const int c0e = (t & 3) * 8;
  const int wbase = w * 1024;
  const int mRow = (w >> 1) * 64, nCol = (w & 1) * 64;

  const bf16_t* ga0 = A + (size_t)r0 * D_ + c0e;
  const bf16_t* ga1 = A + (size_t)(r0 + 64) * D_ + c0e;
  const bf16_t* gb0 = Bw + (size_t)r0 * D_ + c0e;
  const bf16_t* gb1 = Bw + (size_t)(r0 + 64) * D_ + c0e;

  glds16(ga0, smem + wbase);
  glds16(ga1, smem + 4096 + wbase);
  glds16(gb0, smem + 8192 + wbase);
  glds16(gb1, smem + 12288 + wbase);

  for (int kb = 0; kb < 24; ++kb) {
    __syncthreads();
    char* cur = smem + (kb & 1) * 16384;
    char* nxt = smem + ((kb + 1) & 1) * 16384;
    if (kb < 23) {
      const int ko = (kb + 1) * 32;
      glds16(ga0 + ko, nxt + wbase);
      glds16(ga1 + ko, nxt + 4096 + wbase);
      glds16(gb0 + ko, nxt + 8192 + wbase);
      glds16(gb1 + ko, nxt + 12288 + wbase);
    }
    bf16x8 af[4], bfr[4];
#pragma unroll
    for (int mt = 0; mt < 4; ++mt)
      af[mt] = *(const bf16x8*)(cur + (mRow + mt * 16 + l15) * 64 + quad * 16);
#pragma unroll
    for (int nt = 0; nt < 4; ++nt)
      bfr[nt] = *(const bf16x8*)(cur + 8192 + (nCol + nt * 16 + l15) * 64 +
                                 quad * 16);
#pragma unroll
    for (int mt = 0; mt < 4; ++mt)
#pragma unroll
      for (int nt = 0; nt < 4; ++nt)
        acc[mt][nt] = mfma16(af[mt], bfr[nt], acc[mt][nt]);
  }
}

// ---------------------------------------------------------------------------
// NEW GEMM core: C[256x256] = A[256xK] @ B^T[256xK], K=768, BK=32.
// 512 threads = 8 waves (2 M x 4 N), per-wave output 128x64 (8x4 frags).
// LDS: 4-slot ring, slot = 32KB {A 16KB | B 16KB}, fragment-contiguous:
//   A chunk16 addr = half*8192 + mt*1024 + quad*256 + l15*16
//   B chunk16 addr = 16384 + wc*4096 + nt*1024 + quad*256 + l15*16
// staged via per-lane-permuted GLOBAL source (glds dest linear):
//   A call h: thread(w,lane) <- row h*128 + w*16 + (lane&15), col (lane>>4)*8
//   B call c: thread(w,lane) <- row c*128 + (w>>2)*64+(w&3)*16+(lane&15), same col
// => every ds_read_b128 is lane-linear (0 bank conflicts); global segments
// unchanged vs r13 (16 rows x 64B per wave-op).
// Pipeline: 3 K-tiles ahead; per iter: stage(kt+3) -> 12 ds_read -> 32 MFMA
// -> s_waitcnt vmcnt(8) (counted!) -> raw s_barrier. Slot (kt+3)&3 ==
// (kt-1)&3 was fully read in iter kt-1 (barrier-separated) => no race.
// ---------------------------------------------------------------------------
#define NKT_ 24  // 768/32

__device__ __forceinline__ void gemm_core256(const bf16_t* __restrict__ A,
                                             const bf16_t* __restrict__ Bw,
                                             char* smem, f32x4 (&acc)[8][4]) {
  const int t = threadIdx.x;
  const int lane = t & 63, w = t >> 6;
  const int quad = lane >> 4, l15 = lane & 15;
  const int wr = w >> 2, wc = w & 3;
  const int ldsW = w * 1024;  // wave-uniform

  const bf16_t* gA = A + (size_t)(w * 16 + l15) * D_ + quad * 8;
  const bf16_t* gB = Bw + (size_t)(wr * 64 + wc * 16 + l15) * D_ + quad * 8;

  auto stage = [&](int kt) {
    char* slot = smem + (kt & 3) * 32768;
    const int ko = kt * 32;
    glds16(gA + ko, slot + ldsW);                     // A rows 0..127
    glds16(gA + 128 * D_ + ko, slot + 8192 + ldsW);   // A rows 128..255
    glds16(gB + ko, slot + 16384 + ldsW);             // B rows 0..127
    glds16(gB + 128 * D_ + ko, slot + 24576 + ldsW);  // B rows 128..255
  };

  stage(0); stage(1); stage(2);
  asm volatile("s_waitcnt vmcnt(8)" ::: "memory");  // tile 0 landed
  __builtin_amdgcn_s_barrier();
  asm volatile("" ::: "memory");

  for (int kt = 0; kt < NKT_; ++kt) {
    if (kt < NKT_ - 3) stage(kt + 3);
    const char* slot = smem + (kt & 3) * 32768;
    const char* aBase = slot + wr * 8192 + quad * 256 + l15 * 16;
    const char* bBase = slot + 16384 + wc * 4096 + quad * 256 + l15 * 16;
    bf16x8 af[8], bfr[4];
#pragma unroll
    for (int mt = 0; mt < 8; ++mt)
      af[mt] = *(const bf16x8*)(aBase + mt * 1024);
#pragma unroll
    for (int nt = 0; nt < 4; ++nt)
      bfr[nt] = *(const bf16x8*)(bBase + nt * 1024);
    __builtin_amdgcn_s_setprio(1);
#pragma unroll
    for (int mt = 0; mt < 8; ++mt)
#pragma unroll
      for (int nt = 0; nt < 4; ++nt)
        acc[mt][nt] = mfma16(af[mt], bfr[nt], acc[mt][nt]);
    __builtin_amdgcn_s_setprio(0);
    if (kt < NKT_ - 1) {
      if (kt < NKT_ - 3)
        asm volatile("s_waitcnt vmcnt(8)" ::: "memory");  // tile kt+1 landed
      else if (kt == NKT_ - 3)
        asm volatile("s_waitcnt vmcnt(4)" ::: "memory");
      else
        asm volatile("s_waitcnt vmcnt(0)" ::: "memory");
      __builtin_amdgcn_s_barrier();
      asm volatile("" ::: "memory");
    }
  }
}

__device__ __forceinline__ void zero_acc(f32x4 (&acc)[4][4]) {
  const f32x4 z = {0.f, 0.f, 0.f, 0.f};
#pragma unroll
  for (int a = 0; a < 4; ++a)
#pragma unroll
    for (int b = 0; b < 4; ++b) acc[a][b] = z;
}

// Fused QKV GEMM on the 256^2 core. grid = 576 flat (64 rowblk x 9 tiles),
// bijective chunked XCD swizzle: wg = (bid&7)*72 + (bid>>3) -> 8 rowblks'
// worth of tiles per XCD (X panel L2 reuse). tile = wsel*3 + nb.
__global__ __launch_bounds__(512, 2) void k_gemm_qkv256(
    const bf16_t* __restrict__ X, const bf16_t* __restrict__ Wq,
    const bf16_t* __restrict__ Wk, const bf16_t* __restrict__ Wv,
    const float* __restrict__ bq, const float* __restrict__ bk,
    const float* __restrict__ bv, bf16_t* __restrict__ Q,
    bf16_t* __restrict__ Kb, bf16_t* __restrict__ V) {
  __shared__ alignas(16) char smem[131072];
  const int bid = blockIdx.x;
  const int wg = (bid & 7) * 72 + (bid >> 3);
  const int rowblk = wg / 9, tile = wg % 9;
  const int wsel = tile / 3, nb = tile % 3;
  const bf16_t* W = wsel == 0 ? Wq : wsel == 1 ? Wk : Wv;
  const float* bias = wsel == 0 ? bq : wsel == 1 ? bk : bv;
  bf16_t* Out = wsel == 0 ? Q : wsel == 1 ? Kb : V;

  f32x4 acc[8][4];
  {
    const f32x4 z = {0.f, 0.f, 0.f, 0.f};
#pragma unroll
    for (int a = 0; a < 8; ++a)
#pragma unroll
      for (int b = 0; b < 4; ++b) acc[a][b] = z;
  }
  gemm_core256(X + (size_t)rowblk * 256 * D_, W + (size_t)nb * 256 * D_, smem,
               acc);

  const int lane = threadIdx.x & 63, w = threadIdx.x >> 6;
  const int quad = lane >> 4, l15 = lane & 15;
  const int mbase = rowblk * 256 + (w >> 2) * 128;
  const int nbase = nb * 256 + (w & 3) * 64;
#pragma unroll
  for (int nt = 0; nt < 4; ++nt) {
    const int col = nbase + nt * 16 + l15;
    const float bb = bias[col];
#pragma unroll
    for (int mt = 0; mt < 8; ++mt)
#pragma unroll
      for (int r = 0; r < 4; ++r) {
        const int row = mbase + mt * 16 + quad * 4 + r;
        Out[(size_t)row * D_ + col] = (bf16_t)(acc[mt][nt][r] + bb);
      }
  }
}

// Wo epilogue GEMM on the 256^2 core: out = A @ W^T + bias (f32 out).
// grid = 192 flat (64 rowblk x 3 nb), chunked XCD swizzle (24 per XCD).
__global__ __launch_bounds__(512, 2) void k_gemm_wo256(
    const bf16_t* __restrict__ A, const bf16_t* __restrict__ W,
    const float* __restrict__ bias, float* __restrict__ Out) {
  __shared__ alignas(16) char smem[131072];
  const int bid = blockIdx.x;
  const int wg = (bid & 7) * 24 + (bid >> 3);
  const int rowblk = wg / 3, nb = wg % 3;

  f32x4 acc[8][4];
  {
    const f32x4 z = {0.f, 0.f, 0.f, 0.f};
#pragma unroll
    for (int a = 0; a < 8; ++a)
#pragma unroll
      for (int b = 0; b < 4; ++b) acc[a][b] = z;
  }
  gemm_core256(A + (size_t)rowblk * 256 * D_, W + (size_t)nb * 256 * D_, smem,
               acc);

  const int lane = threadIdx.x & 63, w = threadIdx.x >> 6;
  const int quad = lane >> 4, l15 = lane & 15;
  const int mbase = rowblk * 256 + (w >> 2) * 128;
  const int nbase = nb * 256 + (w & 3) * 64;
#pragma unroll
  for (int nt = 0; nt < 4; ++nt) {
    const int col = nbase + nt * 16 + l15;
    const float bb = bias[col];
#pragma unroll
    for (int mt = 0; mt < 8; ++mt)
#pragma unroll
      for (int r = 0; r < 4; ++r) {
        const int row = mbase + mt * 16 + quad * 4 + r;
        Out[(size_t)row * D_ + col] = acc[mt][nt][r] + bb;
      }
  }
}

// Plain GEMM (old core): Out[Mx768] = A(bf16) @ W(bf16)^T (+bias) (+addA).
// Used only for the two small Mx GEMMs (M=4096). 2D grid (M/128, 6).
__global__ __launch_bounds__(256) void k_gemm_plain(
    const bf16_t* __restrict__ A, const bf16_t* __restrict__ W,
    const float* __restrict__ bias, const bf16_t* __restrict__ addA,
    void* __restrict__ Out, int outF32) {
  __shared__ alignas(16) char smem[32768];
  const int mblk = blockIdx.x, nblk = blockIdx.y;
  f32x4 acc[4][4];
  zero_acc(acc);
  gemm_core(A + (size_t)mblk * 128 * D_, W + (size_t)nblk * 128 * D_, smem,
            acc);
  const int lane = threadIdx.x & 63, w = threadIdx.x >> 6;
  const int quad = lane >> 4, l15 = lane & 15;
  const int mbase = mblk * 128 + (w >> 1) * 64;
  const int nbase = nblk * 128 + (w & 1) * 64;
#pragma unroll
  for (int nt = 0; nt < 4; ++nt) {
    const int col = nbase + nt * 16 + l15;
    const float bb = bias ? bias[col] : 0.f;
#pragma unroll
    for (int mt = 0; mt < 4; ++mt)
#pragma unroll
      for (int r = 0; r < 4; ++r) {
        const int row = mbase + mt * 16 + quad * 4 + r;
        float v = acc[mt][nt][r] + bb;
        if (addA) v += (float)addA[(size_t)row * D_ + col];
        const size_t oi = (size_t)row * D_ + col;
        if (outF32) ((float*)Out)[oi] = v;
        else ((bf16_t*)Out)[oi] = (bf16_t)v;
      }
  }
}

// Segment mean over batch of x (f32 in, bf16 out).
__global__ __launch_bounds__(256) void k_segmean(const float* __restrict__ X,
                                                 const int* __restrict__ tid,
                                                 bf16_t* __restrict__ M) {
  const size_t i = ((size_t)blockIdx.x * 256 + threadIdx.x) * 8;
  float acc[K_][8];
  float cnt[K_];
#pragma unroll
  for (int k = 0; k < K_; ++k) {
    cnt[k] = 0.f;
#pragma unroll
    for (int j = 0; j < 8; ++j) acc[k][j] = 0.f;
  }
  const bool is64 = (tid[1] == 0);
  for (int b = 0; b < B_; ++b) {
    const int s = (is64 ? (int)((const long long*)tid)[b] : tid[b]) - 1;
    const float* p = X + (size_t)b * ND_ + i;
    f32x4 y0 = *(const f32x4*)p;
    f32x4 y1 = *(const f32x4*)(p + 4);
#pragma unroll
    for (int k = 0; k < K_; ++k) {
      const float msk = (s == k) ? 1.f : 0.f;
      cnt[k] += msk;
#pragma unroll
      for (int j = 0; j < 4; ++j) {
        acc[k][j] += msk * y0[j];
        acc[k][4 + j] += msk * y1[j];
      }
    }
  }
#pragma unroll
  for (int k = 0; k < K_; ++k) {
    const float inv = 1.f / fmaxf(cnt[k], 1.f);
    bf16x8 o;
#pragma unroll
    for (int j = 0; j < 8; ++j) o[j] = (bf16_t)(acc[k][j] * inv);
    *(bf16x8*)(M + (size_t)k * ND_ + i) = o;
  }
}

// ---------------------------------------------------------------------------
// Flash attention per (b,h): Out = softmax(Q' @ K'^T / 8) @ V   (EXACT r11)
//   addq==1: queries = Qp + Madd[seg];  addq==2: keys = Kp + Madd[seg]
// No max-subtraction; deferred l-reduction; sigma-permuted keys; K/V register
// prefetch. grid = (4, B*H).
// ---------------------------------------------------------------------------
__global__ __launch_bounds__(256) void k_attn(const bf16_t* __restrict__ Qp,
                                              const bf16_t* __restrict__ Kp,
                                              const bf16_t* __restrict__ Vp,
                                              const bf16_t* __restrict__ Madd,
                                              const int* __restrict__ tid,
                                              bf16_t* __restrict__ Op,
                                              int addq) {
  __shared__ alignas(16) __bf16 Kt[64][72];
  __shared__ alignas(16) __bf16 Vt[64][72];
  __shared__ alignas(16) __bf16 Pl[4][32][72];

  const int lane = threadIdx.x & 63, w = threadIdx.x >> 6;
  const int quad = lane >> 4, l15 = lane & 15;
  const int b = blockIdx.y / H_, h = blockIdx.y % H_;
  const int q0 = blockIdx.x * 128 + w * 32;
  const size_t base = (size_t)b * ND_ + h * HD_;
  const float C = 0.18033688011112042f;  // log2(e) / sqrt(HD)
  const int sg = seg_of(tid, b);
  const bf16_t* Mh = Madd + (size_t)sg * ND_ + h * HD_;

  bf16x8 aq[2][2];
#pragma unroll
  for (int mt = 0; mt < 2; ++mt)
#pragma unroll
    for (int ks = 0; ks < 2; ++ks) {
      const size_t off = (size_t)(q0 + mt * 16 + l15) * D_ + ks * 32 + quad * 8;
      bf16x8 q = *(const bf16x8*)(Qp + base + off);
      if (addq == 1) q = addv8(q, *(const bf16x8*)(Mh + off));
      aq[mt][ks] = q;
    }

  f32x4 O[2][4];
  float lacc[2][4];
  {
    const f32x4 z = {0.f, 0.f, 0.f, 0.f};
#pragma unroll
    for (int mt = 0; mt < 2; ++mt)
#pragma unroll
      for (int nt = 0; nt < 4; ++nt) O[mt][nt] = z;
#pragma unroll
    for (int mt = 0; mt < 2; ++mt)
#pragma unroll
      for (int r = 0; r < 4; ++r) lacc[mt][r] = 0.f;
  }

  const int sr = threadIdx.x >> 2, sc = threadIdx.x & 3;
  const int sig_sr = ((sr & 15) << 2) | (sr >> 4);  // sigma-permuted V column

  bf16x8 kr[2], vr[2];
#pragma unroll
  for (int half = 0; half < 2; ++half) {
    const int cc = sc + half * 4;
    const size_t off = (size_t)sr * D_ + cc * 8;
    bf16x8 kv = *(const bf16x8*)(Kp + base + off);
    if (addq == 2) kv = addv8(kv, *(const bf16x8*)(Mh + off));
    kr[half] = kv;
    vr[half] = *(const bf16x8*)(Vp + base + off);
  }

  for (int c0 = 0; c0 < N_; c0 += 64) {
    __syncthreads();
#pragma unroll
    for (int half = 0; half < 2; ++half) {
      const int cc = sc + half * 4;
      *(bf16x8*)(&Kt[sr][cc * 8]) = kr[half];
#pragma unroll
      for (int j = 0; j < 8; ++j) Vt[cc * 8 + j][sig_sr] = vr[half][j];
    }
    __syncthreads();

    if (c0 + 64 < N_) {
#pragma unroll
      for (int half = 0; half < 2; ++half) {
        const int cc = sc + half * 4;
        const size_t off = (size_t)(c0 + 64 + sr) * D_ + cc * 8;
        bf16x8 kv = *(const bf16x8*)(Kp + base + off);
        if (addq == 2) kv = addv8(kv, *(const bf16x8*)(Mh + off));
        kr[half] = kv;
        vr[half] = *(const bf16x8*)(Vp + base + off);
      }
    }

    f32x4 S[2][4];
    {
      const f32x4 z = {0.f, 0.f, 0.f, 0.f};
#pragma unroll
      for (int mt = 0; mt < 2; ++mt)
#pragma unroll
        for (int nt = 0; nt < 4; ++nt) S[mt][nt] = z;
    }
#pragma unroll
    for (int ks = 0; ks < 2; ++ks) {
      bf16x8 bk[4];
#pragma unroll
      for (int nt = 0; nt < 4; ++nt)
        bk[nt] = *(const bf16x8*)(&Kt[nt * 16 + l15][ks * 32 + quad * 8]);
#pragma unroll
      for (int mt = 0; mt < 2; ++mt)
#pragma unroll
        for (int nt = 0; nt < 4; ++nt)
          S[mt][nt] = mfma16(aq[mt][ks], bk[nt], S[mt][nt]);
    }

#pragma unroll
    for (int mt = 0; mt < 2; ++mt)
#pragma unroll
      for (int r = 0; r < 4; ++r) {
        bf16x4 pk;
#pragma unroll
        for (int nt = 0; nt < 4; ++nt) {
          const float p = exp2f(S[mt][nt][r] * C);
          lacc[mt][r] += p;
          pk[nt] = (bf16_t)p;
        }
        *(bf16x4*)(&Pl[w][mt * 16 + quad * 4 + r][l15 * 4]) = pk;
      }

#pragma unroll
    for (int ks2 = 0; ks2 < 2; ++ks2) {
      bf16x8 ap[2], bv[4];
#pragma unroll
      for (int mt = 0; mt < 2; ++mt)
        ap[mt] = *(const bf16x8*)(&Pl[w][mt * 16 + l15][ks2 * 32 + quad * 8]);
#pragma unroll
      for (int nt2 = 0; nt2 < 4; ++nt2)
        bv[nt2] = *(const bf16x8*)(&Vt[nt2 * 16 + l15][ks2 * 32 + quad * 8]);
#pragma unroll
      for (int mt = 0; mt < 2; ++mt)
#pragma unroll
        for (int nt2 = 0; nt2 < 4; ++nt2)
          O[mt][nt2] = mfma16(ap[mt], bv[nt2], O[mt][nt2]);
    }
  }

#pragma unroll
  for (int mt = 0; mt < 2; ++mt)
#pragma unroll
    for (int r = 0; r < 4; ++r) {
      float l = lacc[mt][r];
#pragma unroll
      for (int d = 1; d < 16; d <<= 1) l += __shfl_xor(l, d);
      const float inv = 1.f / l;
      const size_t row = base + (size_t)(q0 + mt * 16 + quad * 4 + r) * D_;
#pragma unroll
      for (int nt2 = 0; nt2 < 4; ++nt2)
        Op[row + nt2 * 16 + l15] = (bf16_t)(O[mt][nt2][r] * inv);
    }
}

// Fallback: zero d_out (f32 extent). Fingerprint: absmax == max|ref|.
__global__ __launch_bounds__(256) void k_zero(float* __restrict__ out) {
  const size_t i = ((size_t)blockIdx.x * 256 + threadIdx.x) * 8;
  f32x4 z = {0.f, 0.f, 0.f, 0.f};
  *(f32x4*)(out + i) = z;
  *(f32x4*)(out + i + 4) = z;
}

// ---------------------------------------------------------------------------
extern "C" void kernel_launch(void* const* d_in, const int* in_sizes, int n_in,
                              void* d_out, int out_size, void* d_ws,
                              size_t ws_size, hipStream_t stream) {
  const float* x  = (const float*)d_in[0];
  const int*  tid = (const int*)d_in[1];
  const float* Wq = (const float*)d_in[2];
  const float* bq = (const float*)d_in[3];
  const float* Wk = (const float*)d_in[4];
  const float* bk = (const float*)d_in[5];
  const float* Wv = (const float*)d_in[6];
  const float* bv = (const float*)d_in[7];
  const float* Wo = (const float*)d_in[8];
  const float* bo = (const float*)d_in[9];
  const float* Wc = (const float*)d_in[10];
  const float* bc = (const float*)d_in[11];

  const size_t SZ  = (size_t)B_ * ND_ * sizeof(bf16_t);   // 25165824
  const size_t MSZ = (size_t)K_ * ND_ * sizeof(bf16_t);   // 6291456
  const size_t WSZ = (size_t)D_ * D_ * sizeof(bf16_t);    // 1179648
  if (ws_size < 3 * SZ + MSZ + 5 * WSZ) {  // diagnosable fallback
    k_zero<<<6144, 256, 0, stream>>>((float*)d_out);
    return;
  }

  char* ws = (char*)d_ws;
  bf16_t* Qb  = (bf16_t*)(ws);
  bf16_t* Kb  = (bf16_t*)(ws + SZ);
  bf16_t* Vb  = (bf16_t*)(ws + 2 * SZ);
  bf16_t* Mq  = (bf16_t*)(ws + 3 * SZ);
  bf16_t* Wqb = (bf16_t*)(ws + 3 * SZ + MSZ);
  bf16_t* Wkb = (bf16_t*)(ws + 3 * SZ + MSZ + WSZ);
  bf16_t* Wvb = (bf16_t*)(ws + 3 * SZ + MSZ + 2 * WSZ);
  bf16_t* Wcb = (bf16_t*)(ws + 3 * SZ + MSZ + 3 * WSZ);
  bf16_t* Wob = (bf16_t*)(ws + 3 * SZ + MSZ + 4 * WSZ);
  bf16_t* Mx = Qb;              // transient, dead before QKV writes Q
  bf16_t* Mb = Kb;              // transient, dead before QKV writes K
  bf16_t* VT = (bf16_t*)d_out;  // bf16 scratch: first half of d_out
  bf16_t* Xb = (bf16_t*)d_out + (size_t)B_ * ND_;  // second half of d_out
  bf16_t* CTX = Kb;             // K dead after stage-1 attention

  k_cvt_all<<<7584, 256, 0, stream>>>(x, Wq, Wk, Wv, Wc, Wo, Xb, Wqb, Wkb,
                                      Wvb, Wcb, Wob);
  k_segmean<<<192, 256, 0, stream>>>(x, tid, Mx);
  k_gemm_plain<<<dim3(32, 6), 256, 0, stream>>>(Mx, Wcb, bc, Mx, Mb, 0);
  k_gemm_plain<<<dim3(32, 6), 256, 0, stream>>>(Mb, Wqb, nullptr, nullptr, Mq,
                                                0);
  k_gemm_qkv256<<<576, 512, 0, stream>>>(Xb, Wqb, Wkb, Wvb, bq, bk, bv, Qb,
                                         Kb, Vb);
  k_attn<<<dim3(4, B_ * H_), 256, 0, stream>>>(Qb, Kb, Vb, Mq, tid, VT, 1);
  k_attn<<<dim3(4, B_ * H_), 256, 0, stream>>>(Qb, Qb, VT, Mq, tid, CTX, 2);
  k_gemm_wo256<<<192, 512, 0, stream>>>(CTX, Wob, bo, (float*)d_out);
}

// Round 3
// 418.494 us; speedup vs baseline: 1.0162x; 1.0162x over previous
//
#include <hip/hip_runtime.h>
#include <hip/hip_bf16.h>

// Dual-stage topic attention. f32 I/O, bf16 intermediates.
//   Xb = bf16(x); Wb* = bf16(W*)   (one merged cvt dispatch)
//   Mx = segmean(x); Mb = Mx + Mx@Wc^T + bc; Mq = Mb@Wq^T
//   [Q|K|V] = Xb @ [Wq|Wk|Wv]^T + bias
//   T = Q + Mq[seg] (on the fly)
//   VT = attn(T,K,V) -> d_out[0:half) ; CTX = attn(Q,T,VT) -> K slot
//   out = CTX @ Wo^T + bo (f32)
// r15 (single change vs r14, confined to gemm_core256 loop body): the
// coarse per-K-iter schedule [stage-all; read-all; mfma-all; vmcnt;
// barrier] is converted to the m201-template FINE 2-phase interleave per
// K-tile: each phase = {ds_read subtile (8 or 4) || 2 glds stage ->
// s_barrier -> lgkmcnt(0)+sched_barrier -> setprio(1) 16 MFMA setprio(0)
// -> s_barrier}, with the counted vmcnt(4) ONCE per K-tile at the
// boundary (tile kt+1 landed; kt+2's 4 loads stay in flight; vmcnt(0)
// only in the epilogue). r14's post-mortem: coarse phases at 1 block/CU
// = all waves read-burst then MFMA-burst in lockstep (MfmaUtil 21%,
// VALUBusy 11%, idle ~70%) — m196's measured warning. Data layout, ring
// indexing, global addresses identical to r14 (refcheck-passed); T2
// conflict-free layout kept (r14: SQ_LDS_BANK_CONFLICT == 0).

typedef __bf16 bf16_t;
typedef __bf16 bf16x8 __attribute__((ext_vector_type(8)));
typedef __bf16 bf16x4 __attribute__((ext_vector_type(4)));
typedef float f32x4 __attribute__((ext_vector_type(4)));

#define B_ 32
#define N_ 512
#define D_ 768
#define H_ 12
#define HD_ 64
#define K_ 8
#define ND_ (N_ * D_)   // 393216

typedef __attribute__((address_space(1))) unsigned int as1_u32;
typedef __attribute__((address_space(3))) unsigned int as3_u32;

__device__ __forceinline__ void glds16(const void* g, void* l) {
  // async global->LDS, 16B/lane; LDS dest = wave-uniform base + lane*16
  __builtin_amdgcn_global_load_lds((as1_u32*)g, (as3_u32*)l, 16, 0, 0);
}

__device__ __forceinline__ f32x4 mfma16(bf16x8 a, bf16x8 b, f32x4 c) {
  return __builtin_amdgcn_mfma_f32_16x16x32_bf16(a, b, c, 0, 0, 0);
}

__device__ __forceinline__ bf16x8 addv8(bf16x8 a, bf16x8 b) {
  bf16x8 o;
#pragma unroll
  for (int j = 0; j < 8; ++j) o[j] = (bf16_t)((float)a[j] + (float)b[j]);
  return o;
}

// tid int32 or int64; int64 => word[1] (high half of elem0) == 0 (values 1..8).
__device__ __forceinline__ int seg_of(const int* tid, int b) {
  const bool is64 = (tid[1] == 0);
  int v = is64 ? (int)((const long long*)tid)[b] : tid[b];
  return v - 1;
}

// One dispatch: convert X (6144 blocks) + 5 weight matrices (288 each).
__global__ __launch_bounds__(256) void k_cvt_all(
    const float* __restrict__ x, const float* __restrict__ Wq,
    const float* __restrict__ Wk, const float* __restrict__ Wv,
    const float* __restrict__ Wc, const float* __restrict__ Wo,
    bf16_t* __restrict__ Xb, bf16_t* __restrict__ Wqb,
    bf16_t* __restrict__ Wkb, bf16_t* __restrict__ Wvb,
    bf16_t* __restrict__ Wcb, bf16_t* __restrict__ Wob) {
  int bid = blockIdx.x;
  const float* in;
  bf16_t* out;
  if (bid < 6144) {
    in = x; out = Xb;
  } else {
    const int wi = (bid - 6144) / 288;
    bid = (bid - 6144) % 288;
    in = wi == 0 ? Wq : wi == 1 ? Wk : wi == 2 ? Wv : wi == 3 ? Wc : Wo;
    out = wi == 0 ? Wqb : wi == 1 ? Wkb : wi == 2 ? Wvb : wi == 3 ? Wcb : Wob;
  }
  const size_t i = ((size_t)bid * 256 + threadIdx.x) * 8;
  f32x4 a = *(const f32x4*)(in + i);
  f32x4 b = *(const f32x4*)(in + i + 4);
  bf16x8 o;
#pragma unroll
  for (int j = 0; j < 4; ++j) { o[j] = (bf16_t)a[j]; o[4 + j] = (bf16_t)b[j]; }
  *(bf16x8*)(out + i) = o;
}

// ---------------------------------------------------------------------------
// OLD GEMM core (128x128, verified): used only for the two tiny Mx GEMMs.
// ---------------------------------------------------------------------------
__device__ __forceinline__ void gemm_core(const bf16_t* __restrict__ A,
                                          const bf16_t* __restrict__ Bw,
                                          char* smem, f32x4 (&acc)[4][4]) {
  const int t = threadIdx.x;
  const int lane = t & 63, w = t >> 6;
  const int quad = lane >> 4, l15 = lane & 15;
  const int r0 = t >> 2;
  const int c0e = (t & 3) * 8;
  const int wbase = w * 1024;
  const int mRow = (w >> 1) * 64, nCol = (w & 1) * 64;

  const bf16_t* ga0 = A + (size_t)r0 * D_ + c0e;
  const bf16_t* ga1 = A + (size_t)(r0 + 64) * D_ + c0e;
  const bf16_t* gb0 = Bw + (size_t)r0 * D_ + c0e;
  const bf16_t* gb1 = Bw + (size_t)(r0 + 64) * D_ + c0e;

  glds16(ga0, smem + wbase);
  glds16(ga1, smem + 4096 + wbase);
  glds16(gb0, smem + 8192 + wbase);
  glds16(gb1, smem + 12288 + wbase);

  for (int kb = 0; kb < 24; ++kb) {
    __syncthreads();
    char* cur = smem + (kb & 1) * 16384;
    char* nxt = smem + ((kb + 1) & 1) * 16384;
    if (kb < 23) {
      const int ko = (kb + 1) * 32;
      glds16(ga0 + ko, nxt + wbase);
      glds16(ga1 + ko, nxt + 4096 + wbase);
      glds16(gb0 + ko, nxt + 8192 + wbase);
      glds16(gb1 + ko, nxt + 12288 + wbase);
    }
    bf16x8 af[4], bfr[4];
#pragma unroll
    for (int mt = 0; mt < 4; ++mt)
      af[mt] = *(const bf16x8*)(cur + (mRow + mt * 16 + l15) * 64 + quad * 16);
#pragma unroll
    for (int nt = 0; nt < 4; ++nt)
      bfr[nt] = *(const bf16x8*)(cur + 8192 + (nCol + nt * 16 + l15) * 64 +
                                 quad * 16);
#pragma unroll
    for (int mt = 0; mt < 4; ++mt)
#pragma unroll
      for (int nt = 0; nt < 4; ++nt)
        acc[mt][nt] = mfma16(af[mt], bfr[nt], acc[mt][nt]);
  }
}

// ---------------------------------------------------------------------------
// 256^2 GEMM core: C[256x256] = A[256xK] @ B^T[256xK], K=768, BK=32.
// 512 threads = 8 waves (2 M x 4 N), per-wave output 128x64 (8x4 frags).
// LDS: 4-slot ring, slot = 32KB {A 16KB | B 16KB}, fragment-contiguous
// (per-lane-permuted GLOBAL source, glds dest linear => every ds_read_b128
// lane-linear, 0 bank conflicts — r14-verified).
// r15 fine schedule per K-tile (2 phases, 16 MFMA each):
//  ph0: ds_read af0-3+bfr0-3 (8) | stage A(kt+2) (2 glds) | barrier |
//       lgkmcnt(0) | setprio1 16xMFMA(mt0-3) setprio0 | barrier
//  ph1: ds_read af4-7 (4)       | stage B(kt+2) (2 glds) | barrier |
//       lgkmcnt(0) | setprio1 16xMFMA(mt4-7) setprio0 | vmcnt(4) | barrier
// vmcnt(4) = counted: tile kt+1 landed, kt+2's 4 loads stay in flight.
// Races: boundary vmcnt+barrier => all 4 slabs of kt landed before ph0
// reads; stage(kt+2) writes slot (kt-2)&3, last read 2 barrier-gens ago.
// ---------------------------------------------------------------------------
#define NKT_ 24  // 768/32

__device__ __forceinline__ void gemm_core256(const bf16_t* __restrict__ A,
                                             const bf16_t* __restrict__ Bw,
                                             char* smem, f32x4 (&acc)[8][4]) {
  const int t = threadIdx.x;
  const int lane = t & 63, w = t >> 6;
  const int quad = lane >> 4, l15 = lane & 15;
  const int wr = w >> 2, wc = w & 3;
  const int ldsW = w * 1024;  // wave-uniform

  const bf16_t* gA = A + (size_t)(w * 16 + l15) * D_ + quad * 8;
  const bf16_t* gB = Bw + (size_t)(wr * 64 + wc * 16 + l15) * D_ + quad * 8;

  auto stageA = [&](int kt) {  // A slabs (rows 0-127, 128-255) of tile kt
    char* slot = smem + (kt & 3) * 32768;
    const int ko = kt * 32;
    glds16(gA + ko, slot + ldsW);
    glds16(gA + 128 * D_ + ko, slot + 8192 + ldsW);
  };
  auto stageB = [&](int kt) {  // B slabs of tile kt
    char* slot = smem + (kt & 3) * 32768;
    const int ko = kt * 32;
    glds16(gB + ko, slot + 16384 + ldsW);
    glds16(gB + 128 * D_ + ko, slot + 24576 + ldsW);
  };

  // prologue: tiles 0,1 fully staged (8 glds/wave)
  stageA(0); stageB(0);
  stageA(1); stageB(1);
  asm volatile("s_waitcnt vmcnt(4)" ::: "memory");  // tile 0 landed
  __builtin_amdgcn_s_barrier();

  for (int kt = 0; kt < NKT_; ++kt) {
    const char* slot = smem + (kt & 3) * 32768;
    const char* aBase = slot + wr * 8192 + quad * 256 + l15 * 16;
    const char* bBase = slot + 16384 + wc * 4096 + quad * 256 + l15 * 16;
    bf16x8 af[4], bfr[4];

    // ---- phase 0 ----
#pragma unroll
    for (int mt = 0; mt < 4; ++mt)
      af[mt] = *(const bf16x8*)(aBase + mt * 1024);
#pragma unroll
    for (int nt = 0; nt < 4; ++nt)
      bfr[nt] = *(const bf16x8*)(bBase + nt * 1024);
    if (kt < NKT_ - 2) stageA(kt + 2);
    __builtin_amdgcn_s_barrier();
    asm volatile("s_waitcnt lgkmcnt(0)" ::: "memory");
    __builtin_amdgcn_sched_barrier(0);
    __builtin_amdgcn_s_setprio(1);
#pragma unroll
    for (int mt = 0; mt < 4; ++mt)
#pragma unroll
      for (int nt = 0; nt < 4; ++nt)
        acc[mt][nt] = mfma16(af[mt], bfr[nt], acc[mt][nt]);
    __builtin_amdgcn_s_setprio(0);
    __builtin_amdgcn_s_barrier();

    // ---- phase 1 ----
#pragma unroll
    for (int mt = 0; mt < 4; ++mt)
      af[mt] = *(const bf16x8*)(aBase + 4096 + mt * 1024);
    if (kt < NKT_ - 2) stageB(kt + 2);
    __builtin_amdgcn_s_barrier();
    asm volatile("s_waitcnt lgkmcnt(0)" ::: "memory");
    __builtin_amdgcn_sched_barrier(0);
    __builtin_amdgcn_s_setprio(1);
#pragma unroll
    for (int mt = 0; mt < 4; ++mt)
#pragma unroll
      for (int nt = 0; nt < 4; ++nt)
        acc[4 + mt][nt] = mfma16(af[mt], bfr[nt], acc[4 + mt][nt]);
    __builtin_amdgcn_s_setprio(0);
    if (kt < NKT_ - 1) {
      if (kt < NKT_ - 2)
        asm volatile("s_waitcnt vmcnt(4)" ::: "memory");  // tile kt+1 landed
      else
        asm volatile("s_waitcnt vmcnt(0)" ::: "memory");  // epilogue drain
      __builtin_amdgcn_s_barrier();
    }
  }
}

__device__ __forceinline__ void zero_acc(f32x4 (&acc)[4][4]) {
  const f32x4 z = {0.f, 0.f, 0.f, 0.f};
#pragma unroll
  for (int a = 0; a < 4; ++a)
#pragma unroll
    for (int b = 0; b < 4; ++b) acc[a][b] = z;
}

// Fused QKV GEMM on the 256^2 core. grid = 576 flat (64 rowblk x 9 tiles),
// bijective chunked XCD swizzle: wg = (bid&7)*72 + (bid>>3) -> 8 rowblks'
// worth of tiles per XCD (X panel L2 reuse). tile = wsel*3 + nb.
__global__ __launch_bounds__(512, 2) void k_gemm_qkv256(
    const bf16_t* __restrict__ X, const bf16_t* __restrict__ Wq,
    const bf16_t* __restrict__ Wk, const bf16_t* __restrict__ Wv,
    const float* __restrict__ bq, const float* __restrict__ bk,
    const float* __restrict__ bv, bf16_t* __restrict__ Q,
    bf16_t* __restrict__ Kb, bf16_t* __restrict__ V) {
  __shared__ alignas(16) char smem[131072];
  const int bid = blockIdx.x;
  const int wg = (bid & 7) * 72 + (bid >> 3);
  const int rowblk = wg / 9, tile = wg % 9;
  const int wsel = tile / 3, nb = tile % 3;
  const bf16_t* W = wsel == 0 ? Wq : wsel == 1 ? Wk : Wv;
  const float* bias = wsel == 0 ? bq : wsel == 1 ? bk : bv;
  bf16_t* Out = wsel == 0 ? Q : wsel == 1 ? Kb : V;

  f32x4 acc[8][4];
  {
    const f32x4 z = {0.f, 0.f, 0.f, 0.f};
#pragma unroll
    for (int a = 0; a < 8; ++a)
#pragma unroll
      for (int b = 0; b < 4; ++b) acc[a][b] = z;
  }
  gemm_core256(X + (size_t)rowblk * 256 * D_, W + (size_t)nb * 256 * D_, smem,
               acc);

  const int lane = threadIdx.x & 63, w = threadIdx.x >> 6;
  const int quad = lane >> 4, l15 = lane & 15;
  const int mbase = rowblk * 256 + (w >> 2) * 128;
  const int nbase = nb * 256 + (w & 3) * 64;
#pragma unroll
  for (int nt = 0; nt < 4; ++nt) {
    const int col = nbase + nt * 16 + l15;
    const float bb = bias[col];
#pragma unroll
    for (int mt = 0; mt < 8; ++mt)
#pragma unroll
      for (int r = 0; r < 4; ++r) {
        const int row = mbase + mt * 16 + quad * 4 + r;
        Out[(size_t)row * D_ + col] = (bf16_t)(acc[mt][nt][r] + bb);
      }
  }
}

// Wo epilogue GEMM on the 256^2 core: out = A @ W^T + bias (f32 out).
// grid = 192 flat (64 rowblk x 3 nb), chunked XCD swizzle (24 per XCD).
__global__ __launch_bounds__(512, 2) void k_gemm_wo256(
    const bf16_t* __restrict__ A, const bf16_t* __restrict__ W,
    const float* __restrict__ bias, float* __restrict__ Out) {
  __shared__ alignas(16) char smem[131072];
  const int bid = blockIdx.x;
  const int wg = (bid & 7) * 24 + (bid >> 3);
  const int rowblk = wg / 3, nb = wg % 3;

  f32x4 acc[8][4];
  {
    const f32x4 z = {0.f, 0.f, 0.f, 0.f};
#pragma unroll
    for (int a = 0; a < 8; ++a)
#pragma unroll
      for (int b = 0; b < 4; ++b) acc[a][b] = z;
  }
  gemm_core256(A + (size_t)rowblk * 256 * D_, W + (size_t)nb * 256 * D_, smem,
               acc);

  const int lane = threadIdx.x & 63, w = threadIdx.x >> 6;
  const int quad = lane >> 4, l15 = lane & 15;
  const int mbase = rowblk * 256 + (w >> 2) * 128;
  const int nbase = nb * 256 + (w & 3) * 64;
#pragma unroll
  for (int nt = 0; nt < 4; ++nt) {
    const int col = nbase + nt * 16 + l15;
    const float bb = bias[col];
#pragma unroll
    for (int mt = 0; mt < 8; ++mt)
#pragma unroll
      for (int r = 0; r < 4; ++r) {
        const int row = mbase + mt * 16 + quad * 4 + r;
        Out[(size_t)row * D_ + col] = acc[mt][nt][r] + bb;
      }
  }
}

// Plain GEMM (old core): Out[Mx768] = A(bf16) @ W(bf16)^T (+bias) (+addA).
// Used only for the two small Mx GEMMs (M=4096). 2D grid (M/128, 6).
__global__ __launch_bounds__(256) void k_gemm_plain(
    const bf16_t* __restrict__ A, const bf16_t* __restrict__ W,
    const float* __restrict__ bias, const bf16_t* __restrict__ addA,
    void* __restrict__ Out, int outF32) {
  __shared__ alignas(16) char smem[32768];
  const int mblk = blockIdx.x, nblk = blockIdx.y;
  f32x4 acc[4][4];
  zero_acc(acc);
  gemm_core(A + (size_t)mblk * 128 * D_, W + (size_t)nblk * 128 * D_, smem,
            acc);
  const int lane = threadIdx.x & 63, w = threadIdx.x >> 6;
  const int quad = lane >> 4, l15 = lane & 15;
  const int mbase = mblk * 128 + (w >> 1) * 64;
  const int nbase = nblk * 128 + (w & 1) * 64;
#pragma unroll
  for (int nt = 0; nt < 4; ++nt) {
    const int col = nbase + nt * 16 + l15;
    const float bb = bias ? bias[col] : 0.f;
#pragma unroll
    for (int mt = 0; mt < 4; ++mt)
#pragma unroll
      for (int r = 0; r < 4; ++r) {
        const int row = mbase + mt * 16 + quad * 4 + r;
        float v = acc[mt][nt][r] + bb;
        if (addA) v += (float)addA[(size_t)row * D_ + col];
        const size_t oi = (size_t)row * D_ + col;
        if (outF32) ((float*)Out)[oi] = v;
        else ((bf16_t*)Out)[oi] = (bf16_t)v;
      }
  }
}

// Segment mean over batch of x (f32 in, bf16 out).
__global__ __launch_bounds__(256) void k_segmean(const float* __restrict__ X,
                                                 const int* __restrict__ tid,
                                                 bf16_t* __restrict__ M) {
  const size_t i = ((size_t)blockIdx.x * 256 + threadIdx.x) * 8;
  float acc[K_][8];
  float cnt[K_];
#pragma unroll
  for (int k = 0; k < K_; ++k) {
    cnt[k] = 0.f;
#pragma unroll
    for (int j = 0; j < 8; ++j) acc[k][j] = 0.f;
  }
  const bool is64 = (tid[1] == 0);
  for (int b = 0; b < B_; ++b) {
    const int s = (is64 ? (int)((const long long*)tid)[b] : tid[b]) - 1;
    const float* p = X + (size_t)b * ND_ + i;
    f32x4 y0 = *(const f32x4*)p;
    f32x4 y1 = *(const f32x4*)(p + 4);
#pragma unroll
    for (int k = 0; k < K_; ++k) {
      const float msk = (s == k) ? 1.f : 0.f;
      cnt[k] += msk;
#pragma unroll
      for (int j = 0; j < 4; ++j) {
        acc[k][j] += msk * y0[j];
        acc[k][4 + j] += msk * y1[j];
      }
    }
  }
#pragma unroll
  for (int k = 0; k < K_; ++k) {
    const float inv = 1.f / fmaxf(cnt[k], 1.f);
    bf16x8 o;
#pragma unroll
    for (int j = 0; j < 8; ++j) o[j] = (bf16_t)(acc[k][j] * inv);
    *(bf16x8*)(M + (size_t)k * ND_ + i) = o;
  }
}

// ---------------------------------------------------------------------------
// Flash attention per (b,h): Out = softmax(Q' @ K'^T / 8) @ V   (EXACT r11)
//   addq==1: queries = Qp + Madd[seg];  addq==2: keys = Kp + Madd[seg]
// No max-subtraction; deferred l-reduction; sigma-permuted keys; K/V register
// prefetch. grid = (4, B*H).
// ---------------------------------------------------------------------------
__global__ __launch_bounds__(256) void k_attn(const bf16_t* __restrict__ Qp,
                                              const bf16_t* __restrict__ Kp,
                                              const bf16_t* __restrict__ Vp,
                                              const bf16_t* __restrict__ Madd,
                                              const int* __restrict__ tid,
                                              bf16_t* __restrict__ Op,
                                              int addq) {
  __shared__ alignas(16) __bf16 Kt[64][72];
  __shared__ alignas(16) __bf16 Vt[64][72];
  __shared__ alignas(16) __bf16 Pl[4][32][72];

  const int lane = threadIdx.x & 63, w = threadIdx.x >> 6;
  const int quad = lane >> 4, l15 = lane & 15;
  const int b = blockIdx.y / H_, h = blockIdx.y % H_;
  const int q0 = blockIdx.x * 128 + w * 32;
  const size_t base = (size_t)b * ND_ + h * HD_;
  const float C = 0.18033688011112042f;  // log2(e) / sqrt(HD)
  const int sg = seg_of(tid, b);
  const bf16_t* Mh = Madd + (size_t)sg * ND_ + h * HD_;

  bf16x8 aq[2][2];
#pragma unroll
  for (int mt = 0; mt < 2; ++mt)
#pragma unroll
    for (int ks = 0; ks < 2; ++ks) {
      const size_t off = (size_t)(q0 + mt * 16 + l15) * D_ + ks * 32 + quad * 8;
      bf16x8 q = *(const bf16x8*)(Qp + base + off);
      if (addq == 1) q = addv8(q, *(const bf16x8*)(Mh + off));
      aq[mt][ks] = q;
    }

  f32x4 O[2][4];
  float lacc[2][4];
  {
    const f32x4 z = {0.f, 0.f, 0.f, 0.f};
#pragma unroll
    for (int mt = 0; mt < 2; ++mt)
#pragma unroll
      for (int nt = 0; nt < 4; ++nt) O[mt][nt] = z;
#pragma unroll
    for (int mt = 0; mt < 2; ++mt)
#pragma unroll
      for (int r = 0; r < 4; ++r) lacc[mt][r] = 0.f;
  }

  const int sr = threadIdx.x >> 2, sc = threadIdx.x & 3;
  const int sig_sr = ((sr & 15) << 2) | (sr >> 4);  // sigma-permuted V column

  bf16x8 kr[2], vr[2];
#pragma unroll
  for (int half = 0; half < 2; ++half) {
    const int cc = sc + half * 4;
    const size_t off = (size_t)sr * D_ + cc * 8;
    bf16x8 kv = *(const bf16x8*)(Kp + base + off);
    if (addq == 2) kv = addv8(kv, *(const bf16x8*)(Mh + off));
    kr[half] = kv;
    vr[half] = *(const bf16x8*)(Vp + base + off);
  }

  for (int c0 = 0; c0 < N_; c0 += 64) {
    __syncthreads();
#pragma unroll
    for (int half = 0; half < 2; ++half) {
      const int cc = sc + half * 4;
      *(bf16x8*)(&Kt[sr][cc * 8]) = kr[half];
#pragma unroll
      for (int j = 0; j < 8; ++j) Vt[cc * 8 + j][sig_sr] = vr[half][j];
    }
    __syncthreads();

    if (c0 + 64 < N_) {
#pragma unroll
      for (int half = 0; half < 2; ++half) {
        const int cc = sc + half * 4;
        const size_t off = (size_t)(c0 + 64 + sr) * D_ + cc * 8;
        bf16x8 kv = *(const bf16x8*)(Kp + base + off);
        if (addq == 2) kv = addv8(kv, *(const bf16x8*)(Mh + off));
        kr[half] = kv;
        vr[half] = *(const bf16x8*)(Vp + base + off);
      }
    }

    f32x4 S[2][4];
    {
      const f32x4 z = {0.f, 0.f, 0.f, 0.f};
#pragma unroll
      for (int mt = 0; mt < 2; ++mt)
#pragma unroll
        for (int nt = 0; nt < 4; ++nt) S[mt][nt] = z;
    }
#pragma unroll
    for (int ks = 0; ks < 2; ++ks) {
      bf16x8 bk[4];
#pragma unroll
      for (int nt = 0; nt < 4; ++nt)
        bk[nt] = *(const bf16x8*)(&Kt[nt * 16 + l15][ks * 32 + quad * 8]);
#pragma unroll
      for (int mt = 0; mt < 2; ++mt)
#pragma unroll
        for (int nt = 0; nt < 4; ++nt)
          S[mt][nt] = mfma16(aq[mt][ks], bk[nt], S[mt][nt]);
    }

#pragma unroll
    for (int mt = 0; mt < 2; ++mt)
#pragma unroll
      for (int r = 0; r < 4; ++r) {
        bf16x4 pk;
#pragma unroll
        for (int nt = 0; nt < 4; ++nt) {
          const float p = exp2f(S[mt][nt][r] * C);
          lacc[mt][r] += p;
          pk[nt] = (bf16_t)p;
        }
        *(bf16x4*)(&Pl[w][mt * 16 + quad * 4 + r][l15 * 4]) = pk;
      }

#pragma unroll
    for (int ks2 = 0; ks2 < 2; ++ks2) {
      bf16x8 ap[2], bv[4];
#pragma unroll
      for (int mt = 0; mt < 2; ++mt)
        ap[mt] = *(const bf16x8*)(&Pl[w][mt * 16 + l15][ks2 * 32 + quad * 8]);
#pragma unroll
      for (int nt2 = 0; nt2 < 4; ++nt2)
        bv[nt2] = *(const bf16x8*)(&Vt[nt2 * 16 + l15][ks2 * 32 + quad * 8]);
#pragma unroll
      for (int mt = 0; mt < 2; ++mt)
#pragma unroll
        for (int nt2 = 0; nt2 < 4; ++nt2)
          O[mt][nt2] = mfma16(ap[mt], bv[nt2], O[mt][nt2]);
    }
  }

#pragma unroll
  for (int mt = 0; mt < 2; ++mt)
#pragma unroll
    for (int r = 0; r < 4; ++r) {
      float l = lacc[mt][r];
#pragma unroll
      for (int d = 1; d < 16; d <<= 1) l += __shfl_xor(l, d);
      const float inv = 1.f / l;
      const size_t row = base + (size_t)(q0 + mt * 16 + quad * 4 + r) * D_;
#pragma unroll
      for (int nt2 = 0; nt2 < 4; ++nt2)
        Op[row + nt2 * 16 + l15] = (bf16_t)(O[mt][nt2][r] * inv);
    }
}

// Fallback: zero d_out (f32 extent). Fingerprint: absmax == max|ref|.
__global__ __launch_bounds__(256) void k_zero(float* __restrict__ out) {
  const size_t i = ((size_t)blockIdx.x * 256 + threadIdx.x) * 8;
  f32x4 z = {0.f, 0.f, 0.f, 0.f};
  *(f32x4*)(out + i) = z;
  *(f32x4*)(out + i + 4) = z;
}

// ---------------------------------------------------------------------------
extern "C" void kernel_launch(void* const* d_in, const int* in_sizes, int n_in,
                              void* d_out, int out_size, void* d_ws,
                              size_t ws_size, hipStream_t stream) {
  const float* x  = (const float*)d_in[0];
  const int*  tid = (const int*)d_in[1];
  const float* Wq = (const float*)d_in[2];
  const float* bq = (const float*)d_in[3];
  const float* Wk = (const float*)d_in[4];
  const float* bk = (const float*)d_in[5];
  const float* Wv = (const float*)d_in[6];
  const float* bv = (const float*)d_in[7];
  const float* Wo = (const float*)d_in[8];
  const float* bo = (const float*)d_in[9];
  const float* Wc = (const float*)d_in[10];
  const float* bc = (const float*)d_in[11];

  const size_t SZ  = (size_t)B_ * ND_ * sizeof(bf16_t);   // 25165824
  const size_t MSZ = (size_t)K_ * ND_ * sizeof(bf16_t);   // 6291456
  const size_t WSZ = (size_t)D_ * D_ * sizeof(bf16_t);    // 1179648
  if (ws_size < 3 * SZ + MSZ + 5 * WSZ) {  // diagnosable fallback
    k_zero<<<6144, 256, 0, stream>>>((float*)d_out);
    return;
  }

  char* ws = (char*)d_ws;
  bf16_t* Qb  = (bf16_t*)(ws);
  bf16_t* Kb  = (bf16_t*)(ws + SZ);
  bf16_t* Vb  = (bf16_t*)(ws + 2 * SZ);
  bf16_t* Mq  = (bf16_t*)(ws + 3 * SZ);
  bf16_t* Wqb = (bf16_t*)(ws + 3 * SZ + MSZ);
  bf16_t* Wkb = (bf16_t*)(ws + 3 * SZ + MSZ + WSZ);
  bf16_t* Wvb = (bf16_t*)(ws + 3 * SZ + MSZ + 2 * WSZ);
  bf16_t* Wcb = (bf16_t*)(ws + 3 * SZ + MSZ + 3 * WSZ);
  bf16_t* Wob = (bf16_t*)(ws + 3 * SZ + MSZ + 4 * WSZ);
  bf16_t* Mx = Qb;              // transient, dead before QKV writes Q
  bf16_t* Mb = Kb;              // transient, dead before QKV writes K
  bf16_t* VT = (bf16_t*)d_out;  // bf16 scratch: first half of d_out
  bf16_t* Xb = (bf16_t*)d_out + (size_t)B_ * ND_;  // second half of d_out
  bf16_t* CTX = Kb;             // K dead after stage-1 attention

  k_cvt_all<<<7584, 256, 0, stream>>>(x, Wq, Wk, Wv, Wc, Wo, Xb, Wqb, Wkb,
                                      Wvb, Wcb, Wob);
  k_segmean<<<192, 256, 0, stream>>>(x, tid, Mx);
  k_gemm_plain<<<dim3(32, 6), 256, 0, stream>>>(Mx, Wcb, bc, Mx, Mb, 0);
  k_gemm_plain<<<dim3(32, 6), 256, 0, stream>>>(Mb, Wqb, nullptr, nullptr, Mq,
                                                0);
  k_gemm_qkv256<<<576, 512, 0, stream>>>(Xb, Wqb, Wkb, Wvb, bq, bk, bv, Qb,
                                         Kb, Vb);
  k_attn<<<dim3(4, B_ * H_), 256, 0, stream>>>(Qb, Kb, Vb, Mq, tid, VT, 1);
  k_attn<<<dim3(4, B_ * H_), 256, 0, stream>>>(Qb, Qb, VT, Mq, tid, CTX, 2);
  k_gemm_wo256<<<192, 512, 0, stream>>>(CTX, Wob, bo, (float*)d_out);
}